// Round 2
// baseline (3457.895 us; speedup 1.0000x reference)
//
#include <hip/hip_runtime.h>

#define S 2048
#define HID 2048
#define NH 16
#define NKV 4
#define D 128
#define GR 4  // q-heads per kv group
#define SCALE 0.08838834764831845f  // 1/sqrt(128)

// ---------------- GEMM: C[M,N] = A[M,K] * B[K,N], f32 ----------------------
// 128x128 tile, BK=16, 256 threads, 8x8 per thread, reg-prefetched loads.
#define BK 16

struct GemmLds {
  float As[BK][132];  // [k][m], +4 pad: rows stay 16B-aligned (528B), banks ok
  float Bs[BK][132];  // [k][n]
};

__device__ __forceinline__ void gemm_body(const float* __restrict__ A,
                                          const float* __restrict__ B,
                                          float* __restrict__ C,
                                          int N, int K, int m0, int n0,
                                          GemmLds& L, int t) {
  const int tx = t & 15, ty = t >> 4;
  const int am = t >> 1;        // A row in tile (0..127), 2 threads/row
  const int ak = (t & 1) * 8;   // A col (0 or 8)
  const int bk = t >> 4;        // B row in tile (0..15)
  const int bn = (t & 15) * 8;  // B col, multiple of 8

  float acc[8][8] = {};

  float4 ra0 = *(const float4*)(A + (size_t)(m0 + am) * K + ak);
  float4 ra1 = *(const float4*)(A + (size_t)(m0 + am) * K + ak + 4);
  float4 rb0 = *(const float4*)(B + (size_t)bk * N + n0 + bn);
  float4 rb1 = *(const float4*)(B + (size_t)bk * N + n0 + bn + 4);

  for (int k0 = 0; k0 < K; k0 += BK) {
    __syncthreads();  // previous iteration's LDS reads done
    L.As[ak + 0][am] = ra0.x; L.As[ak + 1][am] = ra0.y;
    L.As[ak + 2][am] = ra0.z; L.As[ak + 3][am] = ra0.w;
    L.As[ak + 4][am] = ra1.x; L.As[ak + 5][am] = ra1.y;
    L.As[ak + 6][am] = ra1.z; L.As[ak + 7][am] = ra1.w;
    *(float4*)&L.Bs[bk][bn] = rb0;
    *(float4*)&L.Bs[bk][bn + 4] = rb1;
    __syncthreads();
    if (k0 + BK < K) {  // prefetch next tile; overlaps with inner loop
      ra0 = *(const float4*)(A + (size_t)(m0 + am) * K + (k0 + BK) + ak);
      ra1 = *(const float4*)(A + (size_t)(m0 + am) * K + (k0 + BK) + ak + 4);
      rb0 = *(const float4*)(B + (size_t)(k0 + BK + bk) * N + n0 + bn);
      rb1 = *(const float4*)(B + (size_t)(k0 + BK + bk) * N + n0 + bn + 4);
    }
#pragma unroll
    for (int kk = 0; kk < BK; ++kk) {
      float4 a0 = *(const float4*)&L.As[kk][ty * 4];
      float4 a1 = *(const float4*)&L.As[kk][64 + ty * 4];
      float4 b0 = *(const float4*)&L.Bs[kk][tx * 4];
      float4 b1 = *(const float4*)&L.Bs[kk][64 + tx * 4];
      float av[8] = {a0.x, a0.y, a0.z, a0.w, a1.x, a1.y, a1.z, a1.w};
      float bv[8] = {b0.x, b0.y, b0.z, b0.w, b1.x, b1.y, b1.z, b1.w};
#pragma unroll
      for (int i = 0; i < 8; ++i)
#pragma unroll
        for (int j = 0; j < 8; ++j) acc[i][j] += av[i] * bv[j];
    }
  }
#pragma unroll
  for (int i = 0; i < 8; ++i) {
    int m = m0 + ((i < 4) ? (ty * 4 + i) : (64 + ty * 4 + (i - 4)));
    float* crow = C + (size_t)m * N + n0;
    *(float4*)(crow + tx * 4)      = make_float4(acc[i][0], acc[i][1], acc[i][2], acc[i][3]);
    *(float4*)(crow + 64 + tx * 4) = make_float4(acc[i][4], acc[i][5], acc[i][6], acc[i][7]);
  }
}

__global__ __launch_bounds__(256) void k_gemm(const float* __restrict__ A,
                                              const float* __restrict__ B,
                                              float* __restrict__ C, int N, int K) {
  __shared__ GemmLds L;
  gemm_body(A, B, C, N, K, blockIdx.y * 128, blockIdx.x * 128, L, threadIdx.x);
}

// Fused QKV: one launch (grid 24x16) so Wk/Wv GEMMs don't idle 3/4 of the CUs.
__global__ __launch_bounds__(256) void k_gemm_qkv(const float* __restrict__ A,
                                                  const float* __restrict__ Wq,
                                                  const float* __restrict__ Wk,
                                                  const float* __restrict__ Wv,
                                                  float* Qb, float* Kb, float* Vb) {
  __shared__ GemmLds L;
  const int bx = blockIdx.x;
  const float* B; float* C; int N, n0;
  if (bx < 16)      { B = Wq; C = Qb; N = 2048; n0 = bx * 128; }
  else if (bx < 20) { B = Wk; C = Kb; N = 512;  n0 = (bx - 16) * 128; }
  else              { B = Wv; C = Vb; N = 512;  n0 = (bx - 20) * 128; }
  gemm_body(A, B, C, N, 2048, blockIdx.y * 128, n0, L, threadIdx.x);
}

// ------------- per-(s,head) RMSNorm + RoPE, in-place on f32 [S][nh*128] -----
__global__ __launch_bounds__(128) void k_norm_rope(float* __restrict__ X,
                                                   const float* __restrict__ sc,
                                                   const float* __restrict__ cosp,
                                                   const float* __restrict__ sinp,
                                                   int nh) {
  const int s = blockIdx.x, h = blockIdx.y, d = threadIdx.x;
  float* row = X + ((size_t)s * nh + h) * D;
  float x = row[d];
  float v = x * x;
#pragma unroll
  for (int o = 32; o; o >>= 1) v += __shfl_xor(v, o, 64);
  __shared__ float red[2];
  if ((d & 63) == 0) red[d >> 6] = v;
  __syncthreads();
  float var = (red[0] + red[1]) * (1.0f / 128.0f);
  float rinv = rsqrtf(var + 1e-6f);
  float xn = x * rinv * sc[d];
  __shared__ float sh[D];
  sh[d] = xn;
  __syncthreads();
  float rot = (d < 64) ? -sh[d + 64] : sh[d - 64];
  row[d] = xn * cosp[s * D + d] + rot * sinp[s * D + d];
}

// ---------------- attention: one block per (query row i, kv group g) --------
__device__ __forceinline__ float blockMax256(float v, float* red, int t) {
#pragma unroll
  for (int o = 32; o; o >>= 1) v = fmaxf(v, __shfl_xor(v, o, 64));
  if ((t & 63) == 0) red[t >> 6] = v;
  __syncthreads();
  v = fmaxf(fmaxf(red[0], red[1]), fmaxf(red[2], red[3]));
  __syncthreads();
  return v;
}
__device__ __forceinline__ float blockSum256(float v, float* red, int t) {
#pragma unroll
  for (int o = 32; o; o >>= 1) v += __shfl_xor(v, o, 64);
  if ((t & 63) == 0) red[t >> 6] = v;
  __syncthreads();
  v = red[0] + red[1] + red[2] + red[3];
  __syncthreads();
  return v;
}

__global__ __launch_bounds__(256) void k_attn(const float* __restrict__ Q,
                                              const float* __restrict__ K,
                                              const float* __restrict__ V,
                                              float* __restrict__ O) {
  const int i = blockIdx.x, g = blockIdx.y, t = threadIdx.x;
  __shared__ float qs[GR][D];
  __shared__ float sc[GR][S];
  __shared__ float red[4];
  __shared__ float osum[GR][D];
  for (int idx = t; idx < GR * D; idx += 256) {
    int h = idx >> 7, d = idx & (D - 1);
    qs[h][d] = Q[((size_t)i * NH + g * GR + h) * D + d] * SCALE;
  }
  __syncthreads();

  // phase 1: scores for all 4 heads of the group (K row loaded once)
  float lm0 = -3.4e38f, lm1 = -3.4e38f, lm2 = -3.4e38f, lm3 = -3.4e38f;
  for (int j = t; j <= i; j += 256) {
    const float* kr = K + ((size_t)j * NKV + g) * D;
    float s0 = 0.f, s1 = 0.f, s2 = 0.f, s3 = 0.f;
#pragma unroll
    for (int c = 0; c < 32; ++c) {
      float4 kv = *(const float4*)(kr + c * 4);
      float4 q0 = *(const float4*)&qs[0][c * 4];
      float4 q1 = *(const float4*)&qs[1][c * 4];
      float4 q2 = *(const float4*)&qs[2][c * 4];
      float4 q3 = *(const float4*)&qs[3][c * 4];
      s0 += q0.x * kv.x + q0.y * kv.y + q0.z * kv.z + q0.w * kv.w;
      s1 += q1.x * kv.x + q1.y * kv.y + q1.z * kv.z + q1.w * kv.w;
      s2 += q2.x * kv.x + q2.y * kv.y + q2.z * kv.z + q2.w * kv.w;
      s3 += q3.x * kv.x + q3.y * kv.y + q3.z * kv.z + q3.w * kv.w;
    }
    sc[0][j] = s0; sc[1][j] = s1; sc[2][j] = s2; sc[3][j] = s3;
    lm0 = fmaxf(lm0, s0); lm1 = fmaxf(lm1, s1);
    lm2 = fmaxf(lm2, s2); lm3 = fmaxf(lm3, s3);
  }
  float m0 = blockMax256(lm0, red, t);
  float m1 = blockMax256(lm1, red, t);
  float m2 = blockMax256(lm2, red, t);
  float m3 = blockMax256(lm3, red, t);

  float ls0 = 0.f, ls1 = 0.f, ls2 = 0.f, ls3 = 0.f;
  for (int j = t; j <= i; j += 256) {
    float p0 = __expf(sc[0][j] - m0); sc[0][j] = p0; ls0 += p0;
    float p1 = __expf(sc[1][j] - m1); sc[1][j] = p1; ls1 += p1;
    float p2 = __expf(sc[2][j] - m2); sc[2][j] = p2; ls2 += p2;
    float p3 = __expf(sc[3][j] - m3); sc[3][j] = p3; ls3 += p3;
  }
  float l0 = blockSum256(ls0, red, t);
  float l1 = blockSum256(ls1, red, t);
  float l2 = blockSum256(ls2, red, t);
  float l3 = blockSum256(ls3, red, t);

  // phase 2: o[h][d] = sum_j p[h][j] * V[j][d]; V element loaded once
  const int d = t & (D - 1), half = t >> 7;
  float o0 = 0.f, o1 = 0.f, o2 = 0.f, o3 = 0.f;
  for (int j = half; j <= i; j += 2) {
    float v = V[((size_t)j * NKV + g) * D + d];
    o0 += sc[0][j] * v; o1 += sc[1][j] * v;
    o2 += sc[2][j] * v; o3 += sc[3][j] * v;
  }
  if (!half) { osum[0][d] = o0; osum[1][d] = o1; osum[2][d] = o2; osum[3][d] = o3; }
  __syncthreads();
  if (half)  { osum[0][d] += o0; osum[1][d] += o1; osum[2][d] += o2; osum[3][d] += o3; }
  __syncthreads();
  if (t < D) {
    O[((size_t)i * NH + g * GR + 0) * D + t] = osum[0][t] / l0;
    O[((size_t)i * NH + g * GR + 1) * D + t] = osum[1][t] / l1;
    O[((size_t)i * NH + g * GR + 2) * D + t] = osum[2][t] / l2;
    O[((size_t)i * NH + g * GR + 3) * D + t] = osum[3][t] / l3;
  }
}

// ---------------- final RMSNorm over HIDDEN=2048 ----------------------------
__global__ __launch_bounds__(256) void k_fnorm(const float* __restrict__ X,
                                               const float* __restrict__ sc,
                                               float* __restrict__ out) {
  const int s = blockIdx.x, t = threadIdx.x;
  const float* row = X + (size_t)s * HID;
  float4 r0 = *(const float4*)(row + t * 8);
  float4 r1 = *(const float4*)(row + t * 8 + 4);
  float x[8] = {r0.x, r0.y, r0.z, r0.w, r1.x, r1.y, r1.z, r1.w};
  float ss = 0.f;
#pragma unroll
  for (int ii = 0; ii < 8; ++ii) ss += x[ii] * x[ii];
  __shared__ float red[4];
  float tot = blockSum256(ss, red, t);
  float rinv = rsqrtf(tot * (1.0f / 2048.0f) + 1e-6f);
  float4 s0 = *(const float4*)(sc + t * 8);
  float4 s1 = *(const float4*)(sc + t * 8 + 4);
  float4 w0 = make_float4(x[0] * rinv * s0.x, x[1] * rinv * s0.y,
                          x[2] * rinv * s0.z, x[3] * rinv * s0.w);
  float4 w1 = make_float4(x[4] * rinv * s1.x, x[5] * rinv * s1.y,
                          x[6] * rinv * s1.z, x[7] * rinv * s1.w);
  *(float4*)(out + (size_t)s * HID + t * 8) = w0;
  *(float4*)(out + (size_t)s * HID + t * 8 + 4) = w1;
}

extern "C" void kernel_launch(void* const* d_in, const int* in_sizes, int n_in,
                              void* d_out, int out_size, void* d_ws, size_t ws_size,
                              hipStream_t stream) {
  const float* hidden = (const float*)d_in[0];
  const float* cosp   = (const float*)d_in[1];
  const float* sinp   = (const float*)d_in[2];
  const float* Wq     = (const float*)d_in[3];
  const float* Wk     = (const float*)d_in[4];
  const float* Wv     = (const float*)d_in[5];
  const float* Wo     = (const float*)d_in[6];
  const float* qsc    = (const float*)d_in[7];
  const float* ksc    = (const float*)d_in[8];
  const float* lsc    = (const float*)d_in[9];
  // d_in[10] attention_mask: unused (mask is structurally causal)
  float* out = (float*)d_out;

  char* ws = (char*)d_ws;
  float* Qb = (float*)(ws);                  // [S][NH*D]  f32 16 MiB
  float* Kb = (float*)(ws + (16ull << 20));  // [S][NKV*D] f32  4 MiB
  float* Vb = (float*)(ws + (20ull << 20));  // [S][NKV*D] f32  4 MiB
  float* An = (float*)(ws + (24ull << 20));  // [S][NH*D]  f32 16 MiB
  float* Ob = (float*)(ws);                  // reuse Qb (dead after k_attn)

  k_gemm_qkv<<<dim3(24, 16), 256, 0, stream>>>(hidden, Wq, Wk, Wv, Qb, Kb, Vb);
  k_norm_rope<<<dim3(S, NH), 128, 0, stream>>>(Qb, qsc, cosp, sinp, NH);
  k_norm_rope<<<dim3(S, NKV), 128, 0, stream>>>(Kb, ksc, cosp, sinp, NKV);
  k_attn<<<dim3(S, NKV), 256, 0, stream>>>(Qb, Kb, Vb, An);
  k_gemm<<<dim3(16, 16), 256, 0, stream>>>(An, Wo, Ob, 2048, 2048);
  k_fnorm<<<S, 256, 0, stream>>>(Ob, lsc, out);
}

// Round 3
// 1126.645 us; speedup vs baseline: 3.0692x; 3.0692x over previous
//
#include <hip/hip_runtime.h>

typedef unsigned short u16;
typedef unsigned int u32;

#define S 2048
#define HID 2048
#define NH 16
#define NKV 4
#define D 128
#define SCALE 0.08838834764831845f  // 1/sqrt(128)
#define NEG_INF -3.0e38f

typedef __attribute__((ext_vector_type(8))) short short8;  // 8 bf16 = 4 VGPRs
typedef __attribute__((ext_vector_type(4))) float f32x4;

__device__ __forceinline__ u16 f2bf(float f) {
  union { float f; u32 i; } c; c.f = f;
  u32 x = c.i;
  u32 r = x + 0x7fffu + ((x >> 16) & 1u);  // RNE
  return (u16)(r >> 16);
}

// ---------------- GEMM: C[M,N] = A[M,K] * B[K,N], f32 ----------------------
#define BK 16

struct GemmLds {
  float As[BK][132];
  float Bs[BK][132];
};

__device__ __forceinline__ void gemm_body(const float* __restrict__ A,
                                          const float* __restrict__ B,
                                          float* __restrict__ C,
                                          int N, int K, int m0, int n0,
                                          GemmLds& L, int t) {
  const int tx = t & 15, ty = t >> 4;
  const int am = t >> 1;
  const int ak = (t & 1) * 8;
  const int bk = t >> 4;
  const int bn = (t & 15) * 8;

  float acc[8][8] = {};

  float4 ra0 = *(const float4*)(A + (size_t)(m0 + am) * K + ak);
  float4 ra1 = *(const float4*)(A + (size_t)(m0 + am) * K + ak + 4);
  float4 rb0 = *(const float4*)(B + (size_t)bk * N + n0 + bn);
  float4 rb1 = *(const float4*)(B + (size_t)bk * N + n0 + bn + 4);

  for (int k0 = 0; k0 < K; k0 += BK) {
    __syncthreads();
    L.As[ak + 0][am] = ra0.x; L.As[ak + 1][am] = ra0.y;
    L.As[ak + 2][am] = ra0.z; L.As[ak + 3][am] = ra0.w;
    L.As[ak + 4][am] = ra1.x; L.As[ak + 5][am] = ra1.y;
    L.As[ak + 6][am] = ra1.z; L.As[ak + 7][am] = ra1.w;
    *(float4*)&L.Bs[bk][bn] = rb0;
    *(float4*)&L.Bs[bk][bn + 4] = rb1;
    __syncthreads();
    if (k0 + BK < K) {
      ra0 = *(const float4*)(A + (size_t)(m0 + am) * K + (k0 + BK) + ak);
      ra1 = *(const float4*)(A + (size_t)(m0 + am) * K + (k0 + BK) + ak + 4);
      rb0 = *(const float4*)(B + (size_t)(k0 + BK + bk) * N + n0 + bn);
      rb1 = *(const float4*)(B + (size_t)(k0 + BK + bk) * N + n0 + bn + 4);
    }
#pragma unroll
    for (int kk = 0; kk < BK; ++kk) {
      float4 a0 = *(const float4*)&L.As[kk][ty * 4];
      float4 a1 = *(const float4*)&L.As[kk][64 + ty * 4];
      float4 b0 = *(const float4*)&L.Bs[kk][tx * 4];
      float4 b1 = *(const float4*)&L.Bs[kk][64 + tx * 4];
      float av[8] = {a0.x, a0.y, a0.z, a0.w, a1.x, a1.y, a1.z, a1.w};
      float bv[8] = {b0.x, b0.y, b0.z, b0.w, b1.x, b1.y, b1.z, b1.w};
#pragma unroll
      for (int i = 0; i < 8; ++i)
#pragma unroll
        for (int j = 0; j < 8; ++j) acc[i][j] += av[i] * bv[j];
    }
  }
#pragma unroll
  for (int i = 0; i < 8; ++i) {
    int m = m0 + ((i < 4) ? (ty * 4 + i) : (64 + ty * 4 + (i - 4)));
    float* crow = C + (size_t)m * N + n0;
    *(float4*)(crow + tx * 4)      = make_float4(acc[i][0], acc[i][1], acc[i][2], acc[i][3]);
    *(float4*)(crow + 64 + tx * 4) = make_float4(acc[i][4], acc[i][5], acc[i][6], acc[i][7]);
  }
}

__global__ __launch_bounds__(256) void k_gemm(const float* __restrict__ A,
                                              const float* __restrict__ B,
                                              float* __restrict__ C, int N, int K) {
  __shared__ GemmLds L;
  gemm_body(A, B, C, N, K, blockIdx.y * 128, blockIdx.x * 128, L, threadIdx.x);
}

__global__ __launch_bounds__(256) void k_gemm_qkv(const float* __restrict__ A,
                                                  const float* __restrict__ Wq,
                                                  const float* __restrict__ Wk,
                                                  const float* __restrict__ Wv,
                                                  float* Qb, float* Kb, float* Vb) {
  __shared__ GemmLds L;
  const int bx = blockIdx.x;
  const float* B; float* C; int N, n0;
  if (bx < 16)      { B = Wq; C = Qb; N = 2048; n0 = bx * 128; }
  else if (bx < 20) { B = Wk; C = Kb; N = 512;  n0 = (bx - 16) * 128; }
  else              { B = Wv; C = Vb; N = 512;  n0 = (bx - 20) * 128; }
  gemm_body(A, B, C, N, 2048, blockIdx.y * 128, n0, L, threadIdx.x);
}

// ------------- per-(s,head) RMSNorm + RoPE, in-place on f32 -----------------
__global__ __launch_bounds__(128) void k_norm_rope(float* __restrict__ X,
                                                   const float* __restrict__ sc,
                                                   const float* __restrict__ cosp,
                                                   const float* __restrict__ sinp,
                                                   int nh) {
  const int s = blockIdx.x, h = blockIdx.y, d = threadIdx.x;
  float* row = X + ((size_t)s * nh + h) * D;
  float x = row[d];
  float v = x * x;
#pragma unroll
  for (int o = 32; o; o >>= 1) v += __shfl_xor(v, o, 64);
  __shared__ float red[2];
  if ((d & 63) == 0) red[d >> 6] = v;
  __syncthreads();
  float var = (red[0] + red[1]) * (1.0f / 128.0f);
  float rinv = rsqrtf(var + 1e-6f);
  float xn = x * rinv * sc[d];
  __shared__ float sh[D];
  sh[d] = xn;
  __syncthreads();
  float rot = (d < 64) ? -sh[d + 64] : sh[d - 64];
  row[d] = xn * cosp[s * D + d] + rot * sinp[s * D + d];
}

// ---------------- flash attention, MFMA 16x16x32 bf16 -----------------------
// Block: 128 thr (2 waves). Block bx, head h processes q-tiles {bx, 63-bx}
// (32 rows each) -> uniform 33 key-tiles of work per block.
// Wave w owns 16 q-rows. K/V staged per 64-key tile into LDS as bf16.
#define KPITCH 136  // 272 B rows: 16B-aligned ds_read_b128 for QK B-frags
#define VPITCH 130  // 260 B rows: PV b16 gather bank = quad*8+j+8nc+l15/2 -> conflict-free
#define PPITCH 72   // 144 B rows: aligned b128 A-frag reads

__global__ __launch_bounds__(128) void k_flash(const float* __restrict__ Q,
                                               const float* __restrict__ K,
                                               const float* __restrict__ V,
                                               float* __restrict__ O) {
  const int bx = blockIdx.x, h = blockIdx.y, g = h >> 2;
  const int t = threadIdx.x;
  const int w = t >> 6, lane = t & 63, l15 = lane & 15, quad = lane >> 4;
  const int sl = t & 31, sk = t >> 5;

  __shared__ __align__(16) u16 Klds[64 * KPITCH];
  __shared__ __align__(16) u16 Vlds[64 * VPITCH];
  __shared__ __align__(16) u16 Plds[2][16 * PPITCH];

  for (int ph = 0; ph < 2; ++ph) {
    const int qt = ph ? (63 - bx) : bx;
    const int qbase = qt * 32 + w * 16;

    // Q fragments (A-layout): Q[qbase+l15][c*32 + quad*8 + j] * SCALE, bf16
    short8 qf[4];
    {
      const float* qp = Q + (size_t)(qbase + l15) * HID + h * D + quad * 8;
#pragma unroll
      for (int c = 0; c < 4; ++c) {
        float4 v0 = *(const float4*)(qp + c * 32);
        float4 v1 = *(const float4*)(qp + c * 32 + 4);
        qf[c][0] = (short)f2bf(v0.x * SCALE); qf[c][1] = (short)f2bf(v0.y * SCALE);
        qf[c][2] = (short)f2bf(v0.z * SCALE); qf[c][3] = (short)f2bf(v0.w * SCALE);
        qf[c][4] = (short)f2bf(v1.x * SCALE); qf[c][5] = (short)f2bf(v1.y * SCALE);
        qf[c][6] = (short)f2bf(v1.z * SCALE); qf[c][7] = (short)f2bf(v1.w * SCALE);
      }
    }

    float m[4], l[4];
    f32x4 oacc[8];
#pragma unroll
    for (int r = 0; r < 4; ++r) { m[r] = NEG_INF; l[r] = 0.f; }
#pragma unroll
    for (int nc = 0; nc < 8; ++nc) oacc[nc] = (f32x4){0.f, 0.f, 0.f, 0.f};

    const int nt = (qt >> 1) + 1;
    for (int jt = 0; jt < nt; ++jt) {
      const int j0 = jt * 64;
      __syncthreads();  // previous tile's LDS reads complete
      // ---- stage K,V tile (64 keys x 128 d), f32 -> bf16 ----
      for (int kk = sk; kk < 64; kk += 4) {
        const float* kg = K + ((size_t)(j0 + kk) * NKV + g) * D + sl * 4;
        const float* vg = V + ((size_t)(j0 + kk) * NKV + g) * D + sl * 4;
        float4 kv = *(const float4*)kg;
        float4 vv = *(const float4*)vg;
        ushort4 kw;
        kw.x = f2bf(kv.x); kw.y = f2bf(kv.y); kw.z = f2bf(kv.z); kw.w = f2bf(kv.w);
        *(ushort4*)&Klds[kk * KPITCH + sl * 4] = kw;
        u32 w0 = (u32)f2bf(vv.x) | ((u32)f2bf(vv.y) << 16);
        u32 w1 = (u32)f2bf(vv.z) | ((u32)f2bf(vv.w) << 16);
        *(u32*)&Vlds[kk * VPITCH + sl * 4]     = w0;
        *(u32*)&Vlds[kk * VPITCH + sl * 4 + 2] = w1;
      }
      __syncthreads();

      // ---- QK^T: 4 key sub-tiles x 4 d-chunks ----
      f32x4 sa[4];
#pragma unroll
      for (int sub = 0; sub < 4; ++sub) {
        f32x4 acc = {0.f, 0.f, 0.f, 0.f};
#pragma unroll
        for (int c = 0; c < 4; ++c) {
          short8 kf = *(const short8*)&Klds[(sub * 16 + l15) * KPITCH + c * 32 + quad * 8];
          acc = __builtin_amdgcn_mfma_f32_16x16x32_bf16(qf[c], kf, acc, 0, 0, 0);
        }
        sa[sub] = acc;
      }

      // ---- causal mask (only the diagonal tile needs it) ----
      if (jt == nt - 1) {
#pragma unroll
        for (int sub = 0; sub < 4; ++sub) {
          int key = j0 + sub * 16 + l15;
#pragma unroll
          for (int r = 0; r < 4; ++r)
            if (key > qbase + quad * 4 + r) sa[sub][r] = NEG_INF;
        }
      }

      // ---- online softmax (state per q-row, replicated over 16 row-lanes) ----
      float tmax[4];
#pragma unroll
      for (int r = 0; r < 4; ++r)
        tmax[r] = fmaxf(fmaxf(sa[0][r], sa[1][r]), fmaxf(sa[2][r], sa[3][r]));
#pragma unroll
      for (int r = 0; r < 4; ++r) {
#pragma unroll
        for (int off = 1; off < 16; off <<= 1)
          tmax[r] = fmaxf(tmax[r], __shfl_xor(tmax[r], off, 64));
      }
      float alpha[4], rs[4];
#pragma unroll
      for (int r = 0; r < 4; ++r) {
        float mn = fmaxf(m[r], tmax[r]);
        alpha[r] = __expf(m[r] - mn);
        m[r] = mn;
        rs[r] = 0.f;
      }
#pragma unroll
      for (int sub = 0; sub < 4; ++sub) {
#pragma unroll
        for (int r = 0; r < 4; ++r) {
          float p = __expf(sa[sub][r] - m[r]);
          rs[r] += p;
          Plds[w][(quad * 4 + r) * PPITCH + sub * 16 + l15] = f2bf(p);
        }
      }
#pragma unroll
      for (int r = 0; r < 4; ++r) {
#pragma unroll
        for (int off = 1; off < 16; off <<= 1)
          rs[r] += __shfl_xor(rs[r], off, 64);
        l[r] = l[r] * alpha[r] + rs[r];
      }
#pragma unroll
      for (int nc = 0; nc < 8; ++nc)
#pragma unroll
        for (int r = 0; r < 4; ++r) oacc[nc][r] *= alpha[r];

      // ---- PV: P (A-layout via LDS round-trip) x V tiles ----
#pragma unroll
      for (int kc = 0; kc < 2; ++kc) {
        short8 pf = *(const short8*)&Plds[w][l15 * PPITCH + kc * 32 + quad * 8];
#pragma unroll
        for (int nc = 0; nc < 8; ++nc) {
          short8 vf;
#pragma unroll
          for (int j = 0; j < 8; ++j)
            vf[j] = (short)Vlds[(kc * 32 + quad * 8 + j) * VPITCH + nc * 16 + l15];
          oacc[nc] = __builtin_amdgcn_mfma_f32_16x16x32_bf16(pf, vf, oacc[nc], 0, 0, 0);
        }
      }
    }

    // ---- epilogue: O = acc / l ----
    float inv[4];
#pragma unroll
    for (int r = 0; r < 4; ++r) inv[r] = 1.0f / l[r];
#pragma unroll
    for (int nc = 0; nc < 8; ++nc)
#pragma unroll
      for (int r = 0; r < 4; ++r)
        O[(size_t)(qbase + quad * 4 + r) * HID + h * D + nc * 16 + l15] =
            oacc[nc][r] * inv[r];
  }
}

// ---------------- final RMSNorm over HIDDEN=2048 ----------------------------
__device__ __forceinline__ float blockSum256(float v, float* red, int t) {
#pragma unroll
  for (int o = 32; o; o >>= 1) v += __shfl_xor(v, o, 64);
  if ((t & 63) == 0) red[t >> 6] = v;
  __syncthreads();
  v = red[0] + red[1] + red[2] + red[3];
  __syncthreads();
  return v;
}

__global__ __launch_bounds__(256) void k_fnorm(const float* __restrict__ X,
                                               const float* __restrict__ sc,
                                               float* __restrict__ out) {
  const int s = blockIdx.x, t = threadIdx.x;
  const float* row = X + (size_t)s * HID;
  float4 r0 = *(const float4*)(row + t * 8);
  float4 r1 = *(const float4*)(row + t * 8 + 4);
  float x[8] = {r0.x, r0.y, r0.z, r0.w, r1.x, r1.y, r1.z, r1.w};
  float ss = 0.f;
#pragma unroll
  for (int ii = 0; ii < 8; ++ii) ss += x[ii] * x[ii];
  __shared__ float red[4];
  float tot = blockSum256(ss, red, t);
  float rinv = rsqrtf(tot * (1.0f / 2048.0f) + 1e-6f);
  float4 s0 = *(const float4*)(sc + t * 8);
  float4 s1 = *(const float4*)(sc + t * 8 + 4);
  float4 w0 = make_float4(x[0] * rinv * s0.x, x[1] * rinv * s0.y,
                          x[2] * rinv * s0.z, x[3] * rinv * s0.w);
  float4 w1 = make_float4(x[4] * rinv * s1.x, x[5] * rinv * s1.y,
                          x[6] * rinv * s1.z, x[7] * rinv * s1.w);
  *(float4*)(out + (size_t)s * HID + t * 8) = w0;
  *(float4*)(out + (size_t)s * HID + t * 8 + 4) = w1;
}

extern "C" void kernel_launch(void* const* d_in, const int* in_sizes, int n_in,
                              void* d_out, int out_size, void* d_ws, size_t ws_size,
                              hipStream_t stream) {
  const float* hidden = (const float*)d_in[0];
  const float* cosp   = (const float*)d_in[1];
  const float* sinp   = (const float*)d_in[2];
  const float* Wq     = (const float*)d_in[3];
  const float* Wk     = (const float*)d_in[4];
  const float* Wv     = (const float*)d_in[5];
  const float* Wo     = (const float*)d_in[6];
  const float* qsc    = (const float*)d_in[7];
  const float* ksc    = (const float*)d_in[8];
  const float* lsc    = (const float*)d_in[9];
  float* out = (float*)d_out;

  char* ws = (char*)d_ws;
  float* Qb = (float*)(ws);                  // [S][NH*D]  f32 16 MiB
  float* Kb = (float*)(ws + (16ull << 20));  // [S][NKV*D] f32  4 MiB
  float* Vb = (float*)(ws + (20ull << 20));  // [S][NKV*D] f32  4 MiB
  float* An = (float*)(ws + (24ull << 20));  // [S][NH*D]  f32 16 MiB
  float* Ob = (float*)(ws);                  // reuse Qb (dead after k_flash)

  k_gemm_qkv<<<dim3(24, 16), 256, 0, stream>>>(hidden, Wq, Wk, Wv, Qb, Kb, Vb);
  k_norm_rope<<<dim3(S, NH), 128, 0, stream>>>(Qb, qsc, cosp, sinp, NH);
  k_norm_rope<<<dim3(S, NKV), 128, 0, stream>>>(Kb, ksc, cosp, sinp, NKV);
  k_flash<<<dim3(32, NH), 128, 0, stream>>>(Qb, Kb, Vb, An);
  k_gemm<<<dim3(16, 16), 256, 0, stream>>>(An, Wo, Ob, 2048, 2048);
  k_fnorm<<<S, 256, 0, stream>>>(Ob, lsc, out);
}

// Round 4
// 406.049 us; speedup vs baseline: 8.5160x; 2.7747x over previous
//
#include <hip/hip_runtime.h>

typedef unsigned short u16;
typedef unsigned int u32;

#define S 2048
#define HID 2048
#define NH 16
#define NKV 4
#define D 128
#define QKVP 3072  // QKV buffer pitch (Q|K|V concat per row)
#define SCALE 0.08838834764831845f  // 1/sqrt(128)
#define NEG_INF -3.0e38f

typedef __attribute__((ext_vector_type(8))) short short8;  // 8 bf16 = 4 VGPRs
typedef __attribute__((ext_vector_type(4))) float f32x4;

__device__ __forceinline__ float bf2f(u16 u) {
  union { u32 i; float f; } c; c.i = ((u32)u) << 16; return c.f;
}
__device__ __forceinline__ u16 f2bf(float f) {
  union { float f; u32 i; } c; c.f = f;
  u32 x = c.i;
  u32 r = x + 0x7fffu + ((x >> 16) & 1u);  // RNE
  return (u16)(r >> 16);
}

__device__ __forceinline__ void gload16(const u16* g, u16* l) {
  // async global->LDS, 16B/lane. LDS dest is wave-uniform base + lane*16.
  __builtin_amdgcn_global_load_lds(
      (const __attribute__((address_space(1))) u32*)g,
      (__attribute__((address_space(3))) u32*)l, 16, 0, 0);
}

// ---------------- f32 -> bf16 elementwise convert ---------------------------
__global__ __launch_bounds__(256) void k_cvt(const float* __restrict__ src,
                                             u16* __restrict__ dst) {
  int i = (blockIdx.x * 256 + threadIdx.x) * 8;
  float4 v0 = *(const float4*)(src + i);
  float4 v1 = *(const float4*)(src + i + 4);
  ushort4 w0, w1;
  w0.x = f2bf(v0.x); w0.y = f2bf(v0.y); w0.z = f2bf(v0.z); w0.w = f2bf(v0.w);
  w1.x = f2bf(v1.x); w1.y = f2bf(v1.y); w1.z = f2bf(v1.z); w1.w = f2bf(v1.w);
  *(ushort4*)(dst + i) = w0;
  *(ushort4*)(dst + i + 4) = w1;
}

// ---------------- transpose + convert: W[K][N] f32 -> WT[N][K] bf16 ---------
__global__ __launch_bounds__(256) void k_transpose(const float* __restrict__ src,
                                                   u16* __restrict__ dst,
                                                   int N, int K) {
  __shared__ float T[64][65];
  const int t = threadIdx.x;
  const int nt = blockIdx.x * 64, kt = blockIdx.y * 64;
#pragma unroll
  for (int it = 0; it < 4; ++it) {
    int r = it * 16 + (t >> 4), c = (t & 15) * 4;
    float4 v = *(const float4*)(src + (size_t)(kt + r) * N + nt + c);
    T[r][c] = v.x; T[r][c + 1] = v.y; T[r][c + 2] = v.z; T[r][c + 3] = v.w;
  }
  __syncthreads();
#pragma unroll
  for (int it = 0; it < 2; ++it) {
    int n = it * 32 + (t >> 3), k8 = (t & 7) * 8;
    ushort4 w0, w1;
    w0.x = f2bf(T[k8 + 0][n]); w0.y = f2bf(T[k8 + 1][n]);
    w0.z = f2bf(T[k8 + 2][n]); w0.w = f2bf(T[k8 + 3][n]);
    w1.x = f2bf(T[k8 + 4][n]); w1.y = f2bf(T[k8 + 5][n]);
    w1.z = f2bf(T[k8 + 6][n]); w1.w = f2bf(T[k8 + 7][n]);
    *(ushort4*)(dst + (size_t)(nt + n) * K + kt + k8) = w0;
    *(ushort4*)(dst + (size_t)(nt + n) * K + kt + k8 + 4) = w1;
  }
}

// ---------------- MFMA GEMM: C[M,N] = A[M,K] * BT[N,K]^T, bf16 in -----------
// m97 structure: 128x128 tile, BK=32, 256 thr (4 waves 2x2), global_load_lds
// width 16 staging into unpadded [m][k]/[n][k] LDS, 16 mfma_16x16x32/iter/wave.
__global__ __launch_bounds__(256) void k_gemm_mfma(const u16* __restrict__ A,
                                                   const u16* __restrict__ BT,
                                                   void* __restrict__ Cout,
                                                   int N, int K, int out_bf16) {
  __shared__ __align__(16) u16 As[128 * 32];  // [m][k]: m*32+k
  __shared__ __align__(16) u16 Bs[128 * 32];  // [n][k]: n*32+k
  const int t = threadIdx.x, w = t >> 6, lane = t & 63;
  const int l15 = lane & 15, quad = lane >> 4;
  const int m0 = blockIdx.y * 128, n0 = blockIdx.x * 128;
  const int wr = w >> 1, wc = w & 1;

  // staging: wave w covers LDS bytes [w*1024, w*1024+1024) and +4096
  const int sr = w * 16 + (lane >> 2);   // tile row (0..63), +64 for chunk 2
  const int sk8 = (lane & 3) * 8;        // k offset of this lane's 8 bf16
  const u16* Ag0 = A + (size_t)(m0 + sr) * K + sk8;
  const u16* Ag1 = A + (size_t)(m0 + 64 + sr) * K + sk8;
  const u16* Bg0 = BT + (size_t)(n0 + sr) * K + sk8;
  const u16* Bg1 = BT + (size_t)(n0 + 64 + sr) * K + sk8;
  u16* Al0 = As + w * 512;          // u16 units: 1024 B
  u16* Al1 = As + 2048 + w * 512;
  u16* Bl0 = Bs + w * 512;
  u16* Bl1 = Bs + 2048 + w * 512;

  f32x4 acc[4][4];
#pragma unroll
  for (int i = 0; i < 4; ++i)
#pragma unroll
    for (int j = 0; j < 4; ++j) acc[i][j] = (f32x4){0.f, 0.f, 0.f, 0.f};

  for (int k0 = 0; k0 < K; k0 += 32) {
    __syncthreads();  // previous iteration's ds_reads complete
    gload16(Ag0 + k0, Al0);
    gload16(Ag1 + k0, Al1);
    gload16(Bg0 + k0, Bl0);
    gload16(Bg1 + k0, Bl1);
    __syncthreads();  // drains vmcnt: staged tile visible

    short8 af[4], bf[4];
#pragma unroll
    for (int i = 0; i < 4; ++i)
      af[i] = *(const short8*)&As[(wr * 64 + i * 16 + l15) * 32 + quad * 8];
#pragma unroll
    for (int j = 0; j < 4; ++j)
      bf[j] = *(const short8*)&Bs[(wc * 64 + j * 16 + l15) * 32 + quad * 8];
#pragma unroll
    for (int i = 0; i < 4; ++i)
#pragma unroll
      for (int j = 0; j < 4; ++j)
        acc[i][j] = __builtin_amdgcn_mfma_f32_16x16x32_bf16(af[i], bf[j], acc[i][j], 0, 0, 0);
  }

  // epilogue: C/D layout col=l15, row=quad*4+r
  if (out_bf16) {
    u16* C = (u16*)Cout;
#pragma unroll
    for (int i = 0; i < 4; ++i)
#pragma unroll
      for (int j = 0; j < 4; ++j) {
        int col = n0 + wc * 64 + j * 16 + l15;
#pragma unroll
        for (int r = 0; r < 4; ++r)
          C[(size_t)(m0 + wr * 64 + i * 16 + quad * 4 + r) * N + col] = f2bf(acc[i][j][r]);
      }
  } else {
    float* C = (float*)Cout;
#pragma unroll
    for (int i = 0; i < 4; ++i)
#pragma unroll
      for (int j = 0; j < 4; ++j) {
        int col = n0 + wc * 64 + j * 16 + l15;
#pragma unroll
        for (int r = 0; r < 4; ++r)
          C[(size_t)(m0 + wr * 64 + i * 16 + quad * 4 + r) * N + col] = acc[i][j][r];
      }
  }
}

// ------------- per-(s,head) RMSNorm + RoPE on bf16 rows, pitch QKVP ---------
// scale folds 1/sqrt(D) into Q so flash loads Q fragments with no conversion.
__global__ __launch_bounds__(128) void k_norm_rope(u16* __restrict__ X,
                                                   const float* __restrict__ sc,
                                                   const float* __restrict__ cosp,
                                                   const float* __restrict__ sinp,
                                                   float scale) {
  const int s = blockIdx.x, h = blockIdx.y, d = threadIdx.x;
  u16* row = X + (size_t)s * QKVP + h * D;
  float x = bf2f(row[d]);
  float v = x * x;
#pragma unroll
  for (int o = 32; o; o >>= 1) v += __shfl_xor(v, o, 64);
  __shared__ float red[2];
  if ((d & 63) == 0) red[d >> 6] = v;
  __syncthreads();
  float var = (red[0] + red[1]) * (1.0f / 128.0f);
  float rinv = rsqrtf(var + 1e-6f) * scale;
  float xn = x * rinv * sc[d];
  __shared__ float sh[D];
  sh[d] = xn;
  __syncthreads();
  float rot = (d < 64) ? -sh[d + 64] : sh[d - 64];
  row[d] = f2bf(xn * cosp[s * D + d] + rot * sinp[s * D + d]);
}

// ---------------- flash attention, MFMA 16x16x32 bf16 -----------------------
#define KPITCH 136  // 272 B rows: 16B-aligned ds_read_b128 for QK B-frags
#define VPITCH 130  // 260 B rows: PV b16 gather conflict-free
#define PPITCH 72   // 144 B rows: aligned b128 A-frag reads

__global__ __launch_bounds__(128) void k_flash(const u16* __restrict__ QKV,
                                               u16* __restrict__ O) {
  const int bx = blockIdx.x, h = blockIdx.y, g = h >> 2;
  const int t = threadIdx.x;
  const int w = t >> 6, lane = t & 63, l15 = lane & 15, quad = lane >> 4;
  const int sl = t & 15, sk = t >> 4;

  __shared__ __align__(16) u16 Klds[64 * KPITCH];
  __shared__ __align__(16) u16 Vlds[64 * VPITCH];
  __shared__ __align__(16) u16 Plds[2][16 * PPITCH];

  for (int ph = 0; ph < 2; ++ph) {
    const int qt = ph ? (63 - bx) : bx;
    const int qbase = qt * 32 + w * 16;

    // Q fragments (A-layout), pre-scaled by 1/sqrt(D) in k_norm_rope
    short8 qf[4];
    {
      const u16* qp = QKV + (size_t)(qbase + l15) * QKVP + h * D + quad * 8;
#pragma unroll
      for (int c = 0; c < 4; ++c) qf[c] = *(const short8*)(qp + c * 32);
    }

    float m[4], l[4];
    f32x4 oacc[8];
#pragma unroll
    for (int r = 0; r < 4; ++r) { m[r] = NEG_INF; l[r] = 0.f; }
#pragma unroll
    for (int nc = 0; nc < 8; ++nc) oacc[nc] = (f32x4){0.f, 0.f, 0.f, 0.f};

    const int nt = (qt >> 1) + 1;
    for (int jt = 0; jt < nt; ++jt) {
      const int j0 = jt * 64;
      __syncthreads();
      // ---- stage K,V tile (64 keys x 128 d), bf16 straight copy ----
      for (int kk = sk; kk < 64; kk += 8) {
        const u16* kg = QKV + (size_t)(j0 + kk) * QKVP + 2048 + g * D + sl * 8;
        uint4 kv = *(const uint4*)kg;
        uint4 vv = *(const uint4*)(kg + 512);  // V is 512 u16 after K
        *(uint4*)&Klds[kk * KPITCH + sl * 8] = kv;
        u32* vp = (u32*)&Vlds[kk * VPITCH + sl * 8];  // 4B-aligned only
        vp[0] = vv.x; vp[1] = vv.y; vp[2] = vv.z; vp[3] = vv.w;
      }
      __syncthreads();

      // ---- QK^T ----
      f32x4 sa[4];
#pragma unroll
      for (int sub = 0; sub < 4; ++sub) {
        f32x4 acc = {0.f, 0.f, 0.f, 0.f};
#pragma unroll
        for (int c = 0; c < 4; ++c) {
          short8 kf = *(const short8*)&Klds[(sub * 16 + l15) * KPITCH + c * 32 + quad * 8];
          acc = __builtin_amdgcn_mfma_f32_16x16x32_bf16(qf[c], kf, acc, 0, 0, 0);
        }
        sa[sub] = acc;
      }

      // ---- causal mask (diagonal tile only) ----
      if (jt == nt - 1) {
#pragma unroll
        for (int sub = 0; sub < 4; ++sub) {
          int key = j0 + sub * 16 + l15;
#pragma unroll
          for (int r = 0; r < 4; ++r)
            if (key > qbase + quad * 4 + r) sa[sub][r] = NEG_INF;
        }
      }

      // ---- online softmax ----
      float tmax[4];
#pragma unroll
      for (int r = 0; r < 4; ++r)
        tmax[r] = fmaxf(fmaxf(sa[0][r], sa[1][r]), fmaxf(sa[2][r], sa[3][r]));
#pragma unroll
      for (int r = 0; r < 4; ++r) {
#pragma unroll
        for (int off = 1; off < 16; off <<= 1)
          tmax[r] = fmaxf(tmax[r], __shfl_xor(tmax[r], off, 64));
      }
      float alpha[4], rs[4];
#pragma unroll
      for (int r = 0; r < 4; ++r) {
        float mn = fmaxf(m[r], tmax[r]);
        alpha[r] = __expf(m[r] - mn);
        m[r] = mn;
        rs[r] = 0.f;
      }
#pragma unroll
      for (int sub = 0; sub < 4; ++sub) {
#pragma unroll
        for (int r = 0; r < 4; ++r) {
          float p = __expf(sa[sub][r] - m[r]);
          rs[r] += p;
          Plds[w][(quad * 4 + r) * PPITCH + sub * 16 + l15] = f2bf(p);
        }
      }
#pragma unroll
      for (int r = 0; r < 4; ++r) {
#pragma unroll
        for (int off = 1; off < 16; off <<= 1)
          rs[r] += __shfl_xor(rs[r], off, 64);
        l[r] = l[r] * alpha[r] + rs[r];
      }
#pragma unroll
      for (int nc = 0; nc < 8; ++nc)
#pragma unroll
        for (int r = 0; r < 4; ++r) oacc[nc][r] *= alpha[r];

      // ---- PV ----
#pragma unroll
      for (int kc = 0; kc < 2; ++kc) {
        short8 pf = *(const short8*)&Plds[w][l15 * PPITCH + kc * 32 + quad * 8];
#pragma unroll
        for (int nc = 0; nc < 8; ++nc) {
          short8 vf;
#pragma unroll
          for (int j = 0; j < 8; ++j)
            vf[j] = (short)Vlds[(kc * 32 + quad * 8 + j) * VPITCH + nc * 16 + l15];
          oacc[nc] = __builtin_amdgcn_mfma_f32_16x16x32_bf16(pf, vf, oacc[nc], 0, 0, 0);
        }
      }
    }

    // ---- epilogue: O = acc / l, bf16 (feeds Wo GEMM's global_load_lds) ----
    float inv[4];
#pragma unroll
    for (int r = 0; r < 4; ++r) inv[r] = 1.0f / l[r];
#pragma unroll
    for (int nc = 0; nc < 8; ++nc)
#pragma unroll
      for (int r = 0; r < 4; ++r)
        O[(size_t)(qbase + quad * 4 + r) * HID + h * D + nc * 16 + l15] =
            f2bf(oacc[nc][r] * inv[r]);
  }
}

// ---------------- final RMSNorm over HIDDEN=2048 ----------------------------
__device__ __forceinline__ float blockSum256(float v, float* red, int t) {
#pragma unroll
  for (int o = 32; o; o >>= 1) v += __shfl_xor(v, o, 64);
  if ((t & 63) == 0) red[t >> 6] = v;
  __syncthreads();
  v = red[0] + red[1] + red[2] + red[3];
  __syncthreads();
  return v;
}

__global__ __launch_bounds__(256) void k_fnorm(const float* __restrict__ X,
                                               const float* __restrict__ sc,
                                               float* __restrict__ out) {
  const int s = blockIdx.x, t = threadIdx.x;
  const float* row = X + (size_t)s * HID;
  float4 r0 = *(const float4*)(row + t * 8);
  float4 r1 = *(const float4*)(row + t * 8 + 4);
  float x[8] = {r0.x, r0.y, r0.z, r0.w, r1.x, r1.y, r1.z, r1.w};
  float ss = 0.f;
#pragma unroll
  for (int ii = 0; ii < 8; ++ii) ss += x[ii] * x[ii];
  __shared__ float red[4];
  float tot = blockSum256(ss, red, t);
  float rinv = rsqrtf(tot * (1.0f / 2048.0f) + 1e-6f);
  float4 s0 = *(const float4*)(sc + t * 8);
  float4 s1 = *(const float4*)(sc + t * 8 + 4);
  float4 w0 = make_float4(x[0] * rinv * s0.x, x[1] * rinv * s0.y,
                          x[2] * rinv * s0.z, x[3] * rinv * s0.w);
  float4 w1 = make_float4(x[4] * rinv * s1.x, x[5] * rinv * s1.y,
                          x[6] * rinv * s1.z, x[7] * rinv * s1.w);
  *(float4*)(out + (size_t)s * HID + t * 8) = w0;
  *(float4*)(out + (size_t)s * HID + t * 8 + 4) = w1;
}

extern "C" void kernel_launch(void* const* d_in, const int* in_sizes, int n_in,
                              void* d_out, int out_size, void* d_ws, size_t ws_size,
                              hipStream_t stream) {
  const float* hidden = (const float*)d_in[0];
  const float* cosp   = (const float*)d_in[1];
  const float* sinp   = (const float*)d_in[2];
  const float* Wq     = (const float*)d_in[3];
  const float* Wk     = (const float*)d_in[4];
  const float* Wv     = (const float*)d_in[5];
  const float* Wo     = (const float*)d_in[6];
  const float* qsc    = (const float*)d_in[7];
  const float* ksc    = (const float*)d_in[8];
  const float* lsc    = (const float*)d_in[9];
  float* out = (float*)d_out;

  char* ws = (char*)d_ws;
  u16*   Hb  = (u16*)(ws);                   // [S][HID] bf16, 8 MiB
  u16*   WoT = (u16*)(ws);                   // overlays Hb (after QKV GEMM)
  u16*   WT  = (u16*)(ws + (8ull << 20));    // [3072][2048] bf16, 12 MiB
  u16*   An  = (u16*)(ws + (8ull << 20));    // overlays WT (after QKV GEMM)
  u16*   QKV = (u16*)(ws + (20ull << 20));   // [S][3072] bf16, 12 MiB
  float* Ob  = (float*)(ws + (20ull << 20)); // overlays QKV (after flash)

  k_cvt<<<S * HID / (256 * 8), 256, 0, stream>>>(hidden, Hb);
  k_transpose<<<dim3(32, 32), 256, 0, stream>>>(Wq, WT, 2048, 2048);
  k_transpose<<<dim3(8, 32),  256, 0, stream>>>(Wk, WT + 2048ull * 2048, 512, 2048);
  k_transpose<<<dim3(8, 32),  256, 0, stream>>>(Wv, WT + 2560ull * 2048, 512, 2048);
  k_gemm_mfma<<<dim3(24, 16), 256, 0, stream>>>(Hb, WT, QKV, QKVP, 2048, 1);
  k_transpose<<<dim3(32, 32), 256, 0, stream>>>(Wo, WoT, 2048, 2048);  // after Hb dead
  k_norm_rope<<<dim3(S, NH),  128, 0, stream>>>(QKV, qsc, cosp, sinp, SCALE);
  k_norm_rope<<<dim3(S, NKV), 128, 0, stream>>>(QKV + 2048, ksc, cosp, sinp, 1.0f);
  k_flash<<<dim3(32, NH), 128, 0, stream>>>(QKV, An);
  k_gemm_mfma<<<dim3(16, 16), 256, 0, stream>>>(An, WoT, Ob, 2048, 2048, 0);
  k_fnorm<<<S, 256, 0, stream>>>(Ob, lsc, out);
}

// Round 5
// 386.945 us; speedup vs baseline: 8.9364x; 1.0494x over previous
//
#include <hip/hip_runtime.h>

typedef unsigned short u16;
typedef unsigned int u32;

#define S 2048
#define HID 2048
#define NH 16
#define NKV 4
#define D 128
#define QKVP 3072  // QKV buffer pitch (Q|K|V concat per row)
#define SCALE 0.08838834764831845f  // 1/sqrt(128)
#define NEG_INF -3.0e38f

typedef __attribute__((ext_vector_type(8))) short short8;  // 8 bf16 = 4 VGPRs
typedef __attribute__((ext_vector_type(4))) float f32x4;

__device__ __forceinline__ float bf2f(u16 u) {
  union { u32 i; float f; } c; c.i = ((u32)u) << 16; return c.f;
}
__device__ __forceinline__ u16 f2bf(float f) {
  union { float f; u32 i; } c; c.f = f;
  u32 x = c.i;
  u32 r = x + 0x7fffu + ((x >> 16) & 1u);  // RNE
  return (u16)(r >> 16);
}

__device__ __forceinline__ void gload16(const u16* g, u16* l) {
  __builtin_amdgcn_global_load_lds(
      (const __attribute__((address_space(1))) u32*)g,
      (__attribute__((address_space(3))) u32*)l, 16, 0, 0);
}

// ---------------- f32 -> bf16 elementwise convert ---------------------------
__global__ __launch_bounds__(256) void k_cvt(const float* __restrict__ src,
                                             u16* __restrict__ dst) {
  int i = (blockIdx.x * 256 + threadIdx.x) * 8;
  float4 v0 = *(const float4*)(src + i);
  float4 v1 = *(const float4*)(src + i + 4);
  ushort4 w0, w1;
  w0.x = f2bf(v0.x); w0.y = f2bf(v0.y); w0.z = f2bf(v0.z); w0.w = f2bf(v0.w);
  w1.x = f2bf(v1.x); w1.y = f2bf(v1.y); w1.z = f2bf(v1.z); w1.w = f2bf(v1.w);
  *(ushort4*)(dst + i) = w0;
  *(ushort4*)(dst + i + 4) = w1;
}

// ---------------- transpose + convert: W[K][N] f32 -> WT[N][K] bf16 ---------
__global__ __launch_bounds__(256) void k_transpose(const float* __restrict__ src,
                                                   u16* __restrict__ dst,
                                                   int N, int K) {
  __shared__ float T[64][65];
  const int t = threadIdx.x;
  const int nt = blockIdx.x * 64, kt = blockIdx.y * 64;
#pragma unroll
  for (int it = 0; it < 4; ++it) {
    int r = it * 16 + (t >> 4), c = (t & 15) * 4;
    float4 v = *(const float4*)(src + (size_t)(kt + r) * N + nt + c);
    T[r][c] = v.x; T[r][c + 1] = v.y; T[r][c + 2] = v.z; T[r][c + 3] = v.w;
  }
  __syncthreads();
#pragma unroll
  for (int it = 0; it < 2; ++it) {
    int n = it * 32 + (t >> 3), k8 = (t & 7) * 8;
    ushort4 w0, w1;
    w0.x = f2bf(T[k8 + 0][n]); w0.y = f2bf(T[k8 + 1][n]);
    w0.z = f2bf(T[k8 + 2][n]); w0.w = f2bf(T[k8 + 3][n]);
    w1.x = f2bf(T[k8 + 4][n]); w1.y = f2bf(T[k8 + 5][n]);
    w1.z = f2bf(T[k8 + 6][n]); w1.w = f2bf(T[k8 + 7][n]);
    *(ushort4*)(dst + (size_t)(nt + n) * K + kt + k8) = w0;
    *(ushort4*)(dst + (size_t)(nt + n) * K + kt + k8 + 4) = w1;
  }
}

// ------- V transpose: QKV V-section [s][2560+gd] bf16 -> Vt[gd][s] bf16 -----
__global__ __launch_bounds__(256) void k_vt(const u16* __restrict__ QKV,
                                            u16* __restrict__ Vt) {
  __shared__ u16 T[64][66];
  const int t = threadIdx.x;
  const int s0 = blockIdx.x * 64, d0 = blockIdx.y * 64;
#pragma unroll
  for (int it = 0; it < 4; ++it) {
    int r = it * 16 + (t >> 4), c = (t & 15) * 4;
    ushort4 v = *(const ushort4*)(QKV + (size_t)(s0 + r) * QKVP + 2560 + d0 + c);
    T[r][c] = v.x; T[r][c + 1] = v.y; T[r][c + 2] = v.z; T[r][c + 3] = v.w;
  }
  __syncthreads();
#pragma unroll
  for (int it = 0; it < 4; ++it) {
    int dd = it * 16 + (t >> 4), sc = (t & 15) * 4;
    ushort4 w;
    w.x = T[sc + 0][dd]; w.y = T[sc + 1][dd];
    w.z = T[sc + 2][dd]; w.w = T[sc + 3][dd];
    *(ushort4*)(Vt + (size_t)(d0 + dd) * S + s0 + sc) = w;
  }
}

// ---------------- MFMA GEMM (m97 structure), bf16 in ------------------------
__global__ __launch_bounds__(256) void k_gemm_mfma(const u16* __restrict__ A,
                                                   const u16* __restrict__ BT,
                                                   void* __restrict__ Cout,
                                                   int N, int K, int out_bf16) {
  __shared__ __align__(16) u16 As[128 * 32];
  __shared__ __align__(16) u16 Bs[128 * 32];
  const int t = threadIdx.x, w = t >> 6, lane = t & 63;
  const int l15 = lane & 15, quad = lane >> 4;
  const int m0 = blockIdx.y * 128, n0 = blockIdx.x * 128;
  const int wr = w >> 1, wc = w & 1;

  const int sr = w * 16 + (lane >> 2);
  const int sk8 = (lane & 3) * 8;
  const u16* Ag0 = A + (size_t)(m0 + sr) * K + sk8;
  const u16* Ag1 = A + (size_t)(m0 + 64 + sr) * K + sk8;
  const u16* Bg0 = BT + (size_t)(n0 + sr) * K + sk8;
  const u16* Bg1 = BT + (size_t)(n0 + 64 + sr) * K + sk8;
  u16* Al0 = As + w * 512;
  u16* Al1 = As + 2048 + w * 512;
  u16* Bl0 = Bs + w * 512;
  u16* Bl1 = Bs + 2048 + w * 512;

  f32x4 acc[4][4];
#pragma unroll
  for (int i = 0; i < 4; ++i)
#pragma unroll
    for (int j = 0; j < 4; ++j) acc[i][j] = (f32x4){0.f, 0.f, 0.f, 0.f};

  for (int k0 = 0; k0 < K; k0 += 32) {
    __syncthreads();
    gload16(Ag0 + k0, Al0);
    gload16(Ag1 + k0, Al1);
    gload16(Bg0 + k0, Bl0);
    gload16(Bg1 + k0, Bl1);
    __syncthreads();

    short8 af[4], bf[4];
#pragma unroll
    for (int i = 0; i < 4; ++i)
      af[i] = *(const short8*)&As[(wr * 64 + i * 16 + l15) * 32 + quad * 8];
#pragma unroll
    for (int j = 0; j < 4; ++j)
      bf[j] = *(const short8*)&Bs[(wc * 64 + j * 16 + l15) * 32 + quad * 8];
#pragma unroll
    for (int i = 0; i < 4; ++i)
#pragma unroll
      for (int j = 0; j < 4; ++j)
        acc[i][j] = __builtin_amdgcn_mfma_f32_16x16x32_bf16(af[i], bf[j], acc[i][j], 0, 0, 0);
  }

  if (out_bf16) {
    u16* C = (u16*)Cout;
#pragma unroll
    for (int i = 0; i < 4; ++i)
#pragma unroll
      for (int j = 0; j < 4; ++j) {
        int col = n0 + wc * 64 + j * 16 + l15;
#pragma unroll
        for (int r = 0; r < 4; ++r)
          C[(size_t)(m0 + wr * 64 + i * 16 + quad * 4 + r) * N + col] = f2bf(acc[i][j][r]);
      }
  } else {
    float* C = (float*)Cout;
#pragma unroll
    for (int i = 0; i < 4; ++i)
#pragma unroll
      for (int j = 0; j < 4; ++j) {
        int col = n0 + wc * 64 + j * 16 + l15;
#pragma unroll
        for (int r = 0; r < 4; ++r)
          C[(size_t)(m0 + wr * 64 + i * 16 + quad * 4 + r) * N + col] = acc[i][j][r];
      }
  }
}

// ------------- per-(s,head) RMSNorm + RoPE on bf16 rows, pitch QKVP ---------
__global__ __launch_bounds__(128) void k_norm_rope(u16* __restrict__ X,
                                                   const float* __restrict__ sc,
                                                   const float* __restrict__ cosp,
                                                   const float* __restrict__ sinp,
                                                   float scale) {
  const int s = blockIdx.x, h = blockIdx.y, d = threadIdx.x;
  u16* row = X + (size_t)s * QKVP + h * D;
  float x = bf2f(row[d]);
  float v = x * x;
#pragma unroll
  for (int o = 32; o; o >>= 1) v += __shfl_xor(v, o, 64);
  __shared__ float red[2];
  if ((d & 63) == 0) red[d >> 6] = v;
  __syncthreads();
  float var = (red[0] + red[1]) * (1.0f / 128.0f);
  float rinv = rsqrtf(var + 1e-6f) * scale;
  float xn = x * rinv * sc[d];
  __shared__ float sh[D];
  sh[d] = xn;
  __syncthreads();
  float rot = (d < 64) ? -sh[d + 64] : sh[d - 64];
  row[d] = f2bf(xn * cosp[s * D + d] + rot * sinp[s * D + d]);
}

// ---------------- flash attention v2: S^T form, 4 waves, Vt staged ----------
// Block: 256 thr (4 waves) = 64-row q-tile; wave w owns rows qbase..qbase+15.
// S^T = K x Q^T (operand swap): C col = q-row -> softmax needs only 2 shfl,
// per-lane m/l/alpha. PV as O^T = V^T x P^T: Vt A-frags are b128 (swizzled),
// P^T B-frag = 16 scalar reads reused across all 8 d-chunks.
#define KPITCH 136  // u16: 272 B rows -> b128 frag reads 2-way (free)
#define PTP 18      // u16: P^T pitch

__global__ __launch_bounds__(256) void k_flash(const u16* __restrict__ QKV,
                                               const u16* __restrict__ Vt,
                                               u16* __restrict__ O) {
  const int qt = 31 - (int)blockIdx.x;  // heavy tiles dispatch first
  const int h = blockIdx.y, g = h >> 2;
  const int t = threadIdx.x;
  const int w = t >> 6, lane = t & 63, l15 = lane & 15, quad = lane >> 4;

  __shared__ __align__(16) u16 Klds[64 * KPITCH];
  __shared__ __align__(16) u16 Vlds[128 * 64];     // [d][key], XOR-swizzled
  __shared__ __align__(16) u16 Pt[4][64 * PTP];    // [key][q] per wave

  const int qbase = qt * 64 + w * 16;
  const int qrow = qbase + l15;

  // Q fragments (pre-scaled by 1/sqrt(D) in k_norm_rope); used as B operand.
  short8 qf[4];
  {
    const u16* qp = QKV + (size_t)qrow * QKVP + h * D + quad * 8;
#pragma unroll
    for (int c = 0; c < 4; ++c) qf[c] = *(const short8*)(qp + c * 32);
  }

  float m = NEG_INF, l = 0.f;
  f32x4 oacc[8];
#pragma unroll
  for (int nc = 0; nc < 8; ++nc) oacc[nc] = (f32x4){0.f, 0.f, 0.f, 0.f};

  const int nt = qt + 1;
  for (int jt = 0; jt < nt; ++jt) {
    const int j0 = jt * 64;
    __syncthreads();
    // ---- stage K tile [key][d] (4 iters/thread) ----
    {
      const int kk = t >> 4, sl = t & 15;
#pragma unroll
      for (int it = 0; it < 4; ++it) {
        const u16* kg = QKV + (size_t)(j0 + kk + it * 16) * QKVP + 2048 + g * D + sl * 8;
        *(uint4*)&Klds[(kk + it * 16) * KPITCH + sl * 8] = *(const uint4*)kg;
      }
    }
    // ---- stage V^T tile [d][key] with XOR swizzle (4 iters/thread) ----
    {
      const int dd = t >> 3, c = t & 7;
#pragma unroll
      for (int it = 0; it < 4; ++it) {
        int d = dd + it * 32;
        const u16* vg = Vt + (size_t)(g * D + d) * S + j0 + c * 8;
        *(uint4*)&Vlds[d * 64 + ((c ^ (d & 7)) * 8)] = *(const uint4*)vg;
      }
    }
    __syncthreads();

    // ---- S^T = K x Q^T : row = key (quad*4+r), col = q-row (l15) ----
    f32x4 sa[4];
#pragma unroll
    for (int sub = 0; sub < 4; ++sub) {
      f32x4 acc = {0.f, 0.f, 0.f, 0.f};
#pragma unroll
      for (int c = 0; c < 4; ++c) {
        short8 kf = *(const short8*)&Klds[(sub * 16 + l15) * KPITCH + c * 32 + quad * 8];
        acc = __builtin_amdgcn_mfma_f32_16x16x32_bf16(kf, qf[c], acc, 0, 0, 0);
      }
      sa[sub] = acc;
    }

    // ---- causal mask (per-lane: key > qrow) ----
    if (jt == nt - 1) {
#pragma unroll
      for (int sub = 0; sub < 4; ++sub) {
        int keyb = j0 + sub * 16 + quad * 4;
#pragma unroll
        for (int r = 0; r < 4; ++r)
          if (keyb + r > qrow) sa[sub][r] = NEG_INF;
      }
    }

    // ---- online softmax: in-register over 16 keys, cross-quad 2 shfl ----
    float tmax = sa[0][0];
#pragma unroll
    for (int sub = 0; sub < 4; ++sub)
#pragma unroll
      for (int r = 0; r < 4; ++r) tmax = fmaxf(tmax, sa[sub][r]);
    tmax = fmaxf(tmax, __shfl_xor(tmax, 16, 64));
    tmax = fmaxf(tmax, __shfl_xor(tmax, 32, 64));
    float mn = fmaxf(m, tmax);
    float alpha = __expf(m - mn);
    m = mn;
    float rs = 0.f;
#pragma unroll
    for (int sub = 0; sub < 4; ++sub) {
#pragma unroll
      for (int r = 0; r < 4; ++r) {
        float p = __expf(sa[sub][r] - m);
        rs += p;
        Pt[w][(sub * 16 + quad * 4 + r) * PTP + l15] = f2bf(p);
      }
    }
    rs += __shfl_xor(rs, 16, 64);
    rs += __shfl_xor(rs, 32, 64);
    l = l * alpha + rs;
#pragma unroll
    for (int nc = 0; nc < 8; ++nc) {
      oacc[nc][0] *= alpha; oacc[nc][1] *= alpha;
      oacc[nc][2] *= alpha; oacc[nc][3] *= alpha;
    }

    // ---- O^T += V^T x P^T : A = Vt (b128 swizzled), B = P^T (16 scalar) ----
#pragma unroll
    for (int kc = 0; kc < 2; ++kc) {
      short8 pf;
#pragma unroll
      for (int j = 0; j < 8; ++j)
        pf[j] = (short)Pt[w][(kc * 32 + quad * 8 + j) * PTP + l15];
#pragma unroll
      for (int nc = 0; nc < 8; ++nc) {
        int d = nc * 16 + l15;
        short8 vf = *(const short8*)&Vlds[d * 64 + (((kc * 4 + quad) ^ (d & 7)) * 8)];
        oacc[nc] = __builtin_amdgcn_mfma_f32_16x16x32_bf16(vf, pf, oacc[nc], 0, 0, 0);
      }
    }
  }

  // ---- epilogue: O[q][d] = O^T / l ; lane owns q-row l15, d = nc*16+quad*4+r
  float inv = 1.0f / l;
  u16* orow = O + (size_t)qrow * HID + h * D;
#pragma unroll
  for (int nc = 0; nc < 8; ++nc) {
    ushort4 wv;
    wv.x = f2bf(oacc[nc][0] * inv); wv.y = f2bf(oacc[nc][1] * inv);
    wv.z = f2bf(oacc[nc][2] * inv); wv.w = f2bf(oacc[nc][3] * inv);
    *(ushort4*)(orow + nc * 16 + quad * 4) = wv;
  }
}

// ---------------- final RMSNorm over HIDDEN=2048 ----------------------------
__device__ __forceinline__ float blockSum256(float v, float* red, int t) {
#pragma unroll
  for (int o = 32; o; o >>= 1) v += __shfl_xor(v, o, 64);
  if ((t & 63) == 0) red[t >> 6] = v;
  __syncthreads();
  v = red[0] + red[1] + red[2] + red[3];
  __syncthreads();
  return v;
}

__global__ __launch_bounds__(256) void k_fnorm(const float* __restrict__ X,
                                               const float* __restrict__ sc,
                                               float* __restrict__ out) {
  const int s = blockIdx.x, t = threadIdx.x;
  const float* row = X + (size_t)s * HID;
  float4 r0 = *(const float4*)(row + t * 8);
  float4 r1 = *(const float4*)(row + t * 8 + 4);
  float x[8] = {r0.x, r0.y, r0.z, r0.w, r1.x, r1.y, r1.z, r1.w};
  float ss = 0.f;
#pragma unroll
  for (int ii = 0; ii < 8; ++ii) ss += x[ii] * x[ii];
  __shared__ float red[4];
  float tot = blockSum256(ss, red, t);
  float rinv = rsqrtf(tot * (1.0f / 2048.0f) + 1e-6f);
  float4 s0 = *(const float4*)(sc + t * 8);
  float4 s1 = *(const float4*)(sc + t * 8 + 4);
  float4 w0 = make_float4(x[0] * rinv * s0.x, x[1] * rinv * s0.y,
                          x[2] * rinv * s0.z, x[3] * rinv * s0.w);
  float4 w1 = make_float4(x[4] * rinv * s1.x, x[5] * rinv * s1.y,
                          x[6] * rinv * s1.z, x[7] * rinv * s1.w);
  *(float4*)(out + (size_t)s * HID + t * 8) = w0;
  *(float4*)(out + (size_t)s * HID + t * 8 + 4) = w1;
}

extern "C" void kernel_launch(void* const* d_in, const int* in_sizes, int n_in,
                              void* d_out, int out_size, void* d_ws, size_t ws_size,
                              hipStream_t stream) {
  const float* hidden = (const float*)d_in[0];
  const float* cosp   = (const float*)d_in[1];
  const float* sinp   = (const float*)d_in[2];
  const float* Wq     = (const float*)d_in[3];
  const float* Wk     = (const float*)d_in[4];
  const float* Wv     = (const float*)d_in[5];
  const float* Wo     = (const float*)d_in[6];
  const float* qsc    = (const float*)d_in[7];
  const float* ksc    = (const float*)d_in[8];
  const float* lsc    = (const float*)d_in[9];
  float* out = (float*)d_out;

  char* ws = (char*)d_ws;
  u16*   Hb  = (u16*)(ws);                   // [S][HID] bf16, 8 MiB
  u16*   WoT = (u16*)(ws);                   // overlays Hb (after QKV GEMM)
  u16*   WT  = (u16*)(ws + (8ull << 20));    // [3072][2048] bf16, 12 MiB
  u16*   An  = (u16*)(ws + (8ull << 20));    // overlays WT (after QKV GEMM)
  u16*   QKV = (u16*)(ws + (20ull << 20));   // [S][3072] bf16, 12 MiB
  float* Ob  = (float*)(ws + (20ull << 20)); // overlays QKV (after flash)
  u16*   Vtb = (u16*)(ws + (32ull << 20));   // [512][2048] bf16, 2 MiB

  k_cvt<<<S * HID / (256 * 8), 256, 0, stream>>>(hidden, Hb);
  k_transpose<<<dim3(32, 32), 256, 0, stream>>>(Wq, WT, 2048, 2048);
  k_transpose<<<dim3(8, 32),  256, 0, stream>>>(Wk, WT + 2048ull * 2048, 512, 2048);
  k_transpose<<<dim3(8, 32),  256, 0, stream>>>(Wv, WT + 2560ull * 2048, 512, 2048);
  k_gemm_mfma<<<dim3(24, 16), 256, 0, stream>>>(Hb, WT, QKV, QKVP, 2048, 1);
  k_transpose<<<dim3(32, 32), 256, 0, stream>>>(Wo, WoT, 2048, 2048);  // Hb dead
  k_norm_rope<<<dim3(S, NH),  128, 0, stream>>>(QKV, qsc, cosp, sinp, SCALE);
  k_norm_rope<<<dim3(S, NKV), 128, 0, stream>>>(QKV + 2048, ksc, cosp, sinp, 1.0f);
  k_vt<<<dim3(32, 8), 256, 0, stream>>>(QKV, Vtb);
  k_flash<<<dim3(32, NH), 256, 0, stream>>>(QKV, Vtb, An);
  k_gemm_mfma<<<dim3(16, 16), 256, 0, stream>>>(An, WoT, Ob, 2048, 2048, 0);
  k_fnorm<<<S, 256, 0, stream>>>(Ob, lsc, out);
}

// Round 6
// 353.604 us; speedup vs baseline: 9.7790x; 1.0943x over previous
//
#include <hip/hip_runtime.h>

typedef unsigned short u16;
typedef unsigned int u32;

#define S 2048
#define HID 2048
#define NH 16
#define NKV 4
#define D 128
#define QKVP 3072  // QKV buffer pitch (Q|K|V concat per row)
#define SCALE 0.08838834764831845f  // 1/sqrt(128)
#define NEG_INF -3.0e38f

typedef __attribute__((ext_vector_type(8))) short short8;  // 8 bf16 = 4 VGPRs
typedef __attribute__((ext_vector_type(4))) float f32x4;

__device__ __forceinline__ float bf2f(u16 u) {
  union { u32 i; float f; } c; c.i = ((u32)u) << 16; return c.f;
}
__device__ __forceinline__ u16 f2bf(float f) {
  union { float f; u32 i; } c; c.f = f;
  u32 x = c.i;
  u32 r = x + 0x7fffu + ((x >> 16) & 1u);  // RNE
  return (u16)(r >> 16);
}

__device__ __forceinline__ void gload16(const u16* g, u16* l) {
  __builtin_amdgcn_global_load_lds(
      (const __attribute__((address_space(1))) u32*)g,
      (__attribute__((address_space(3))) u32*)l, 16, 0, 0);
}

// ---------------- f32 -> bf16 elementwise convert ---------------------------
__global__ __launch_bounds__(256) void k_cvt(const float* __restrict__ src,
                                             u16* __restrict__ dst) {
  int i = (blockIdx.x * 256 + threadIdx.x) * 8;
  float4 v0 = *(const float4*)(src + i);
  float4 v1 = *(const float4*)(src + i + 4);
  ushort4 w0, w1;
  w0.x = f2bf(v0.x); w0.y = f2bf(v0.y); w0.z = f2bf(v0.z); w0.w = f2bf(v0.w);
  w1.x = f2bf(v1.x); w1.y = f2bf(v1.y); w1.z = f2bf(v1.z); w1.w = f2bf(v1.w);
  *(ushort4*)(dst + i) = w0;
  *(ushort4*)(dst + i + 4) = w1;
}

// ------- transpose + convert body: src[K][N] f32 -> dst[N][K] bf16 ----------
__device__ __forceinline__ void transpose_body(const float* __restrict__ src,
                                               u16* __restrict__ dst,
                                               int N, int K, int nt, int kt,
                                               int t) {
  __shared__ float T[64][65];
#pragma unroll
  for (int it = 0; it < 4; ++it) {
    int r = it * 16 + (t >> 4), c = (t & 15) * 4;
    float4 v = *(const float4*)(src + (size_t)(kt + r) * N + nt + c);
    T[r][c] = v.x; T[r][c + 1] = v.y; T[r][c + 2] = v.z; T[r][c + 3] = v.w;
  }
  __syncthreads();
#pragma unroll
  for (int it = 0; it < 2; ++it) {
    int n = it * 32 + (t >> 3), k8 = (t & 7) * 8;
    ushort4 w0, w1;
    w0.x = f2bf(T[k8 + 0][n]); w0.y = f2bf(T[k8 + 1][n]);
    w0.z = f2bf(T[k8 + 2][n]); w0.w = f2bf(T[k8 + 3][n]);
    w1.x = f2bf(T[k8 + 4][n]); w1.y = f2bf(T[k8 + 5][n]);
    w1.z = f2bf(T[k8 + 6][n]); w1.w = f2bf(T[k8 + 7][n]);
    *(ushort4*)(dst + (size_t)(nt + n) * K + kt + k8) = w0;
    *(ushort4*)(dst + (size_t)(nt + n) * K + kt + k8 + 4) = w1;
  }
}

__global__ __launch_bounds__(256) void k_transpose(const float* __restrict__ src,
                                                   u16* __restrict__ dst,
                                                   int N, int K) {
  transpose_body(src, dst, N, K, blockIdx.x * 64, blockIdx.y * 64, threadIdx.x);
}

// merged Wq|Wk|Wv transpose (one launch)
__global__ __launch_bounds__(256) void k_transpose_qkv(const float* __restrict__ Wq,
                                                       const float* __restrict__ Wk,
                                                       const float* __restrict__ Wv,
                                                       u16* __restrict__ WT) {
  const int bx = blockIdx.x;
  const float* src; u16* dst; int N, nt;
  if (bx < 32)      { src = Wq; dst = WT;                    N = 2048; nt = bx * 64; }
  else if (bx < 40) { src = Wk; dst = WT + 2048ull * 2048;   N = 512;  nt = (bx - 32) * 64; }
  else              { src = Wv; dst = WT + 2560ull * 2048;   N = 512;  nt = (bx - 40) * 64; }
  transpose_body(src, dst, N, 2048, nt, blockIdx.y * 64, threadIdx.x);
}

// ------- V transpose: QKV V-section [s][2560+gd] bf16 -> Vt[gd][s] bf16 -----
__global__ __launch_bounds__(256) void k_vt(const u16* __restrict__ QKV,
                                            u16* __restrict__ Vt) {
  __shared__ u16 T[64][66];
  const int t = threadIdx.x;
  const int s0 = blockIdx.x * 64, d0 = blockIdx.y * 64;
#pragma unroll
  for (int it = 0; it < 4; ++it) {
    int r = it * 16 + (t >> 4), c = (t & 15) * 4;
    ushort4 v = *(const ushort4*)(QKV + (size_t)(s0 + r) * QKVP + 2560 + d0 + c);
    T[r][c] = v.x; T[r][c + 1] = v.y; T[r][c + 2] = v.z; T[r][c + 3] = v.w;
  }
  __syncthreads();
#pragma unroll
  for (int it = 0; it < 4; ++it) {
    int dd = it * 16 + (t >> 4), sc = (t & 15) * 4;
    ushort4 w;
    w.x = T[sc + 0][dd]; w.y = T[sc + 1][dd];
    w.z = T[sc + 2][dd]; w.w = T[sc + 3][dd];
    *(ushort4*)(Vt + (size_t)(d0 + dd) * S + s0 + sc) = w;
  }
}

// ---------------- MFMA GEMM (m97 structure), bf16 in ------------------------
__global__ __launch_bounds__(256) void k_gemm_mfma(const u16* __restrict__ A,
                                                   const u16* __restrict__ BT,
                                                   void* __restrict__ Cout,
                                                   int N, int K, int out_bf16) {
  __shared__ __align__(16) u16 As[128 * 32];
  __shared__ __align__(16) u16 Bs[128 * 32];
  const int t = threadIdx.x, w = t >> 6, lane = t & 63;
  const int l15 = lane & 15, quad = lane >> 4;
  const int m0 = blockIdx.y * 128, n0 = blockIdx.x * 128;
  const int wr = w >> 1, wc = w & 1;

  const int sr = w * 16 + (lane >> 2);
  const int sk8 = (lane & 3) * 8;
  const u16* Ag0 = A + (size_t)(m0 + sr) * K + sk8;
  const u16* Ag1 = A + (size_t)(m0 + 64 + sr) * K + sk8;
  const u16* Bg0 = BT + (size_t)(n0 + sr) * K + sk8;
  const u16* Bg1 = BT + (size_t)(n0 + 64 + sr) * K + sk8;
  u16* Al0 = As + w * 512;
  u16* Al1 = As + 2048 + w * 512;
  u16* Bl0 = Bs + w * 512;
  u16* Bl1 = Bs + 2048 + w * 512;

  f32x4 acc[4][4];
#pragma unroll
  for (int i = 0; i < 4; ++i)
#pragma unroll
    for (int j = 0; j < 4; ++j) acc[i][j] = (f32x4){0.f, 0.f, 0.f, 0.f};

  for (int k0 = 0; k0 < K; k0 += 32) {
    __syncthreads();
    gload16(Ag0 + k0, Al0);
    gload16(Ag1 + k0, Al1);
    gload16(Bg0 + k0, Bl0);
    gload16(Bg1 + k0, Bl1);
    __syncthreads();

    short8 af[4], bf[4];
#pragma unroll
    for (int i = 0; i < 4; ++i)
      af[i] = *(const short8*)&As[(wr * 64 + i * 16 + l15) * 32 + quad * 8];
#pragma unroll
    for (int j = 0; j < 4; ++j)
      bf[j] = *(const short8*)&Bs[(wc * 64 + j * 16 + l15) * 32 + quad * 8];
#pragma unroll
    for (int i = 0; i < 4; ++i)
#pragma unroll
      for (int j = 0; j < 4; ++j)
        acc[i][j] = __builtin_amdgcn_mfma_f32_16x16x32_bf16(af[i], bf[j], acc[i][j], 0, 0, 0);
  }

  if (out_bf16) {
    u16* C = (u16*)Cout;
#pragma unroll
    for (int i = 0; i < 4; ++i)
#pragma unroll
      for (int j = 0; j < 4; ++j) {
        int col = n0 + wc * 64 + j * 16 + l15;
#pragma unroll
        for (int r = 0; r < 4; ++r)
          C[(size_t)(m0 + wr * 64 + i * 16 + quad * 4 + r) * N + col] = f2bf(acc[i][j][r]);
      }
  } else {
    float* C = (float*)Cout;
#pragma unroll
    for (int i = 0; i < 4; ++i)
#pragma unroll
      for (int j = 0; j < 4; ++j) {
        int col = n0 + wc * 64 + j * 16 + l15;
#pragma unroll
        for (int r = 0; r < 4; ++r)
          C[(size_t)(m0 + wr * 64 + i * 16 + quad * 4 + r) * N + col] = acc[i][j][r];
      }
  }
}

// ------------- per-(s,head) RMSNorm + RoPE, Q and K in one launch -----------
__global__ __launch_bounds__(128) void k_norm_rope(u16* __restrict__ QKV,
                                                   const float* __restrict__ qsc,
                                                   const float* __restrict__ ksc,
                                                   const float* __restrict__ cosp,
                                                   const float* __restrict__ sinp) {
  const int s = blockIdx.x, hh = blockIdx.y, d = threadIdx.x;
  u16* row; const float* sc; float scale;
  if (hh < NH) { row = QKV + (size_t)s * QKVP + hh * D;            sc = qsc; scale = SCALE; }
  else         { row = QKV + (size_t)s * QKVP + 2048 + (hh - NH) * D; sc = ksc; scale = 1.0f; }
  float x = bf2f(row[d]);
  float v = x * x;
#pragma unroll
  for (int o = 32; o; o >>= 1) v += __shfl_xor(v, o, 64);
  __shared__ float red[2];
  if ((d & 63) == 0) red[d >> 6] = v;
  __syncthreads();
  float var = (red[0] + red[1]) * (1.0f / 128.0f);
  float rinv = rsqrtf(var + 1e-6f) * scale;
  float xn = x * rinv * sc[d];
  __shared__ float sh[D];
  sh[d] = xn;
  __syncthreads();
  float rot = (d < 64) ? -sh[d + 64] : sh[d - 64];
  row[d] = f2bf(xn * cosp[s * D + d] + rot * sinp[s * D + d]);
}

// ---------------- flash attention v3: pipelined K-DMA + packed P ------------
// Block: 256 thr (4 waves) = 64-row q-tile of one head.
// K: global_load_lds into double-buffered unpadded LDS, SOURCE-chunk-swizzled
//    (chunk ^= row&7) so frag reads are conflict-free; DMA for tile jt+1
//    issues during compute of jt -> latency hidden behind compute.
// V: register-prefetched (ping-pong), written XOR-swizzled.
// P: packed bf16 pairs -> 4 ds_write_b64 + 2 ds_read_b128 per tile/wave.
#define KP 128   // K LDS row pitch (u16), unpadded (DMA requirement)
#define PTP 72   // P pitch (u16): b64-write / b128-read aligned

__global__ __launch_bounds__(256) void k_flash(const u16* __restrict__ QKV,
                                               const u16* __restrict__ Vt,
                                               u16* __restrict__ O) {
  const int qt = 31 - (int)blockIdx.x;  // heavy tiles dispatch first
  const int h = blockIdx.y, g = h >> 2;
  const int t = threadIdx.x;
  const int w = t >> 6, lane = t & 63, l15 = lane & 15, quad = lane >> 4;

  __shared__ __align__(16) u16 Klds[2][64 * KP];
  __shared__ __align__(16) u16 Vlds[128 * 64];     // [d][key], XOR-swizzled
  __shared__ __align__(16) u16 Pt[4][16 * PTP];    // [qcol][key] per wave

  const int qbase = qt * 64 + w * 16;
  const int qrow = qbase + l15;

  short8 qf[4];
  {
    const u16* qp = QKV + (size_t)qrow * QKVP + h * D + quad * 8;
#pragma unroll
    for (int c = 0; c < 4; ++c) qf[c] = *(const short8*)(qp + c * 32);
  }

  float m = NEG_INF, l = 0.f;
  f32x4 oacc[8];
#pragma unroll
  for (int nc = 0; nc < 8; ++nc) oacc[nc] = (f32x4){0.f, 0.f, 0.f, 0.f};

  const int nt = qt + 1;
  const int dd = t >> 3, cc = t & 7;  // V staging coords

  auto KLOAD = [&](int j0, int b) {  // DMA 4 rows per wave per issue
#pragma unroll
    for (int it = 0; it < 4; ++it) {
      int rl = w * 16 + it * 4 + quad;                 // tile-local key row
      int gchunk = (lane & 15) ^ (rl & 7);             // source swizzle
      const u16* gp = QKV + (size_t)(j0 + rl) * QKVP + 2048 + g * D + gchunk * 8;
      gload16(gp, &Klds[b][(w * 16 + it * 4) * KP]);
    }
  };
  auto VLOAD = [&](int j0, uint4* vr) {
#pragma unroll
    for (int it = 0; it < 4; ++it)
      vr[it] = *(const uint4*)(Vt + (size_t)(g * D + dd + it * 32) * S + j0 + cc * 8);
  };
  auto VWRITE = [&](uint4* vr) {
#pragma unroll
    for (int it = 0; it < 4; ++it) {
      int d = dd + it * 32;
      *(uint4*)&Vlds[d * 64 + ((cc ^ (d & 7)) * 8)] = vr[it];
    }
  };
  auto COMPUTE = [&](int jt, int b) {
    const int j0 = jt * 64;
    // ---- S^T = K x Q^T : row = key (quad*4+r +16sub), col = q-row (l15) ----
    f32x4 sa[4];
#pragma unroll
    for (int sub = 0; sub < 4; ++sub) {
      f32x4 acc = {0.f, 0.f, 0.f, 0.f};
#pragma unroll
      for (int c = 0; c < 4; ++c) {
        int ch = (c * 4 + quad) ^ (l15 & 7);  // undo source swizzle
        short8 kf = *(const short8*)&Klds[b][(sub * 16 + l15) * KP + ch * 8];
        acc = __builtin_amdgcn_mfma_f32_16x16x32_bf16(kf, qf[c], acc, 0, 0, 0);
      }
      sa[sub] = acc;
    }
    if (jt == nt - 1) {  // causal mask, diagonal tile only
#pragma unroll
      for (int sub = 0; sub < 4; ++sub) {
        int keyb = j0 + sub * 16 + quad * 4;
#pragma unroll
        for (int r = 0; r < 4; ++r)
          if (keyb + r > qrow) sa[sub][r] = NEG_INF;
      }
    }
    // ---- online softmax (per-lane state, 2 cross-quad shfl per reduce) ----
    float tmax = sa[0][0];
#pragma unroll
    for (int sub = 0; sub < 4; ++sub)
#pragma unroll
      for (int r = 0; r < 4; ++r) tmax = fmaxf(tmax, sa[sub][r]);
    tmax = fmaxf(tmax, __shfl_xor(tmax, 16, 64));
    tmax = fmaxf(tmax, __shfl_xor(tmax, 32, 64));
    float mn = fmaxf(m, tmax);
    float alpha = __expf(m - mn);
    m = mn;
    float rs = 0.f;
#pragma unroll
    for (int sub = 0; sub < 4; ++sub) {
      float p0 = __expf(sa[sub][0] - m);
      float p1 = __expf(sa[sub][1] - m);
      float p2 = __expf(sa[sub][2] - m);
      float p3 = __expf(sa[sub][3] - m);
      rs += (p0 + p1) + (p2 + p3);
      u32 lo = (u32)f2bf(p0) | ((u32)f2bf(p1) << 16);
      u32 hi = (u32)f2bf(p2) | ((u32)f2bf(p3) << 16);
      *(uint2*)&Pt[w][l15 * PTP + sub * 16 + quad * 4] = make_uint2(lo, hi);
    }
    rs += __shfl_xor(rs, 16, 64);
    rs += __shfl_xor(rs, 32, 64);
    l = l * alpha + rs;
#pragma unroll
    for (int nc = 0; nc < 8; ++nc) {
      oacc[nc][0] *= alpha; oacc[nc][1] *= alpha;
      oacc[nc][2] *= alpha; oacc[nc][3] *= alpha;
    }
    // ---- O^T += V^T x P^T ----
#pragma unroll
    for (int kc = 0; kc < 2; ++kc) {
      short8 pf = *(const short8*)&Pt[w][l15 * PTP + kc * 32 + quad * 8];
#pragma unroll
      for (int nc = 0; nc < 8; ++nc) {
        int d = nc * 16 + l15;
        short8 vf = *(const short8*)&Vlds[d * 64 + (((kc * 4 + quad) ^ (d & 7)) * 8)];
        oacc[nc] = __builtin_amdgcn_mfma_f32_16x16x32_bf16(vf, pf, oacc[nc], 0, 0, 0);
      }
    }
  };

  uint4 vrA[4], vrB[4];
  KLOAD(0, 0);
  VLOAD(0, vrA);
  for (int jt = 0; jt < nt; jt += 2) {
    __syncthreads();                       // prev compute done; K(jt) DMA drained
    VWRITE(vrA);
    __syncthreads();                       // V(jt) visible
    if (jt + 1 < nt) { KLOAD((jt + 1) * 64, 1); VLOAD((jt + 1) * 64, vrB); }
    COMPUTE(jt, 0);
    if (jt + 1 < nt) {
      __syncthreads();
      VWRITE(vrB);
      __syncthreads();
      if (jt + 2 < nt) { KLOAD((jt + 2) * 64, 0); VLOAD((jt + 2) * 64, vrA); }
      COMPUTE(jt + 1, 1);
    }
  }

  // ---- epilogue: O[q][d] = O^T / l ----
  float inv = 1.0f / l;
  u16* orow = O + (size_t)qrow * HID + h * D;
#pragma unroll
  for (int nc = 0; nc < 8; ++nc) {
    ushort4 wv;
    wv.x = f2bf(oacc[nc][0] * inv); wv.y = f2bf(oacc[nc][1] * inv);
    wv.z = f2bf(oacc[nc][2] * inv); wv.w = f2bf(oacc[nc][3] * inv);
    *(ushort4*)(orow + nc * 16 + quad * 4) = wv;
  }
}

// ---------------- final RMSNorm over HIDDEN=2048 ----------------------------
__device__ __forceinline__ float blockSum256(float v, float* red, int t) {
#pragma unroll
  for (int o = 32; o; o >>= 1) v += __shfl_xor(v, o, 64);
  if ((t & 63) == 0) red[t >> 6] = v;
  __syncthreads();
  v = red[0] + red[1] + red[2] + red[3];
  __syncthreads();
  return v;
}

__global__ __launch_bounds__(256) void k_fnorm(const float* __restrict__ X,
                                               const float* __restrict__ sc,
                                               float* __restrict__ out) {
  const int s = blockIdx.x, t = threadIdx.x;
  const float* row = X + (size_t)s * HID;
  float4 r0 = *(const float4*)(row + t * 8);
  float4 r1 = *(const float4*)(row + t * 8 + 4);
  float x[8] = {r0.x, r0.y, r0.z, r0.w, r1.x, r1.y, r1.z, r1.w};
  float ss = 0.f;
#pragma unroll
  for (int ii = 0; ii < 8; ++ii) ss += x[ii] * x[ii];
  __shared__ float red[4];
  float tot = blockSum256(ss, red, t);
  float rinv = rsqrtf(tot * (1.0f / 2048.0f) + 1e-6f);
  float4 s0 = *(const float4*)(sc + t * 8);
  float4 s1 = *(const float4*)(sc + t * 8 + 4);
  float4 w0 = make_float4(x[0] * rinv * s0.x, x[1] * rinv * s0.y,
                          x[2] * rinv * s0.z, x[3] * rinv * s0.w);
  float4 w1 = make_float4(x[4] * rinv * s1.x, x[5] * rinv * s1.y,
                          x[6] * rinv * s1.z, x[7] * rinv * s1.w);
  *(float4*)(out + (size_t)s * HID + t * 8) = w0;
  *(float4*)(out + (size_t)s * HID + t * 8 + 4) = w1;
}

extern "C" void kernel_launch(void* const* d_in, const int* in_sizes, int n_in,
                              void* d_out, int out_size, void* d_ws, size_t ws_size,
                              hipStream_t stream) {
  const float* hidden = (const float*)d_in[0];
  const float* cosp   = (const float*)d_in[1];
  const float* sinp   = (const float*)d_in[2];
  const float* Wq     = (const float*)d_in[3];
  const float* Wk     = (const float*)d_in[4];
  const float* Wv     = (const float*)d_in[5];
  const float* Wo     = (const float*)d_in[6];
  const float* qsc    = (const float*)d_in[7];
  const float* ksc    = (const float*)d_in[8];
  const float* lsc    = (const float*)d_in[9];
  float* out = (float*)d_out;

  char* ws = (char*)d_ws;
  u16*   Hb  = (u16*)(ws);                   // [S][HID] bf16, 8 MiB
  u16*   WoT = (u16*)(ws);                   // overlays Hb (after QKV GEMM)
  u16*   WT  = (u16*)(ws + (8ull << 20));    // [3072][2048] bf16, 12 MiB
  u16*   An  = (u16*)(ws + (8ull << 20));    // overlays WT (after QKV GEMM)
  u16*   QKV = (u16*)(ws + (20ull << 20));   // [S][3072] bf16, 12 MiB
  float* Ob  = (float*)(ws + (20ull << 20)); // overlays QKV (after flash)
  u16*   Vtb = (u16*)(ws + (32ull << 20));   // [512][2048] bf16, 2 MiB

  k_cvt<<<S * HID / (256 * 8), 256, 0, stream>>>(hidden, Hb);
  k_transpose_qkv<<<dim3(48, 32), 256, 0, stream>>>(Wq, Wk, Wv, WT);
  k_gemm_mfma<<<dim3(24, 16), 256, 0, stream>>>(Hb, WT, QKV, QKVP, 2048, 1);
  k_transpose<<<dim3(32, 32), 256, 0, stream>>>(Wo, WoT, 2048, 2048);  // Hb dead
  k_norm_rope<<<dim3(S, NH + NKV), 128, 0, stream>>>(QKV, qsc, ksc, cosp, sinp);
  k_vt<<<dim3(32, 8), 256, 0, stream>>>(QKV, Vtb);
  k_flash<<<dim3(32, NH), 256, 0, stream>>>(QKV, Vtb, An);
  k_gemm_mfma<<<dim3(16, 16), 256, 0, stream>>>(An, WoT, Ob, 2048, 2048, 0);
  k_fnorm<<<S, 256, 0, stream>>>(Ob, lsc, out);
}